// Round 12
// baseline (452.692 us; speedup 1.0000x reference)
//
#include <hip/hip_runtime.h>

#define N_NODES 100000
#define E_EDGES 1600000
#define EP_EDGES (E_EDGES + N_NODES)   // 1,700,000 with self loops
#define SLOPE 0.2f
#define BN_EPS 1e-5f
#define NB 8                 // dst buckets (one per XCD)
#define NODES_PER_B 12500
#define NREP 32              // sub-region replicas per bucket
#define SUBREG 8192          // edges per (rep,bucket) sub-region
#define SCATTER_BLKS ((EP_EDGES + 255) / 256)

typedef _Float16 h2 __attribute__((ext_vector_type(2)));

#if defined(__has_builtin)
#if __has_builtin(__builtin_amdgcn_fdot2)
#define HAVE_FDOT2 1
#endif
#endif

__device__ __forceinline__ float fdot2f(h2 a, h2 b, float c) {
#ifdef HAVE_FDOT2
    return __builtin_amdgcn_fdot2(a, b, c, false);
#else
    return c + (float)a[0] * (float)b[0] + (float)a[1] * (float)b[1];
#endif
}
__device__ __forceinline__ h2 bch2(unsigned u) { return __builtin_bit_cast(h2, u); }
__device__ __forceinline__ unsigned bcu(h2 v) { return __builtin_bit_cast(unsigned, v); }
__device__ __forceinline__ h2 habs2(h2 z) {
    return __builtin_bit_cast(h2, (unsigned)(__builtin_bit_cast(unsigned, z) & 0x7fff7fffu));
}
__device__ __forceinline__ h2 shflx_h2(h2 a, int o) {
    return __builtin_bit_cast(h2, __shfl_xor(__builtin_bit_cast(int, a), o, 64));
}

// DPP rotate-reduce: sum across each 16-lane row, pure VALU
template <int CTRL>
__device__ __forceinline__ float dpp_add_step(float v) {
    int r = __builtin_amdgcn_update_dpp(0, __float_as_int(v), CTRL, 0xF, 0xF, false);
    return v + __int_as_float(r);
}
__device__ __forceinline__ float rowsum16(float v) {
    v = dpp_add_step<0x128>(v);
    v = dpp_add_step<0x124>(v);
    v = dpp_add_step<0x122>(v);
    v = dpp_add_step<0x121>(v);
    return v;
}

// ---------- bucket_scatter body (u32-packed edges: (dlocal<<17)|src) ----------
__device__ __forceinline__ void bucket_scatter_body(int bid, const int* __restrict__ src,
                                                    const int* __restrict__ dst,
                                                    int* __restrict__ gcur, unsigned* __restrict__ ebuf) {
    int i = bid * 256 + threadIdx.x;
    int rep = bid & (NREP - 1);
    bool active = i < EP_EDGES;
    int s = 0, d = 0;
    if (i < E_EDGES) { s = src[i]; d = dst[i]; }
    else if (active) { s = i - E_EDGES; d = s; }
    int b = active ? (int)((unsigned)d / NODES_PER_B) : NB;
    unsigned long long lt = (1ull << (threadIdx.x & 63)) - 1ull;
    int rank = 0;
    unsigned long long mymask = 0;
#pragma unroll
    for (int bb = 0; bb < NB; ++bb) {
        unsigned long long m = __ballot(b == bb);
        if (b == bb) { rank = __popcll(m & lt); mymask = m; }
    }
    int leader = mymask ? (__ffsll((long long)mymask) - 1) : 0;
    int lanebit = threadIdx.x & 63;
    int chunkbase = 0;
    if (active && lanebit == leader)
        chunkbase = atomicAdd(&gcur[rep * NB + b], (int)__popcll(mymask));
    chunkbase = __shfl(chunkbase, leader, 64);
    if (active) {
        unsigned dl = (unsigned)d - (unsigned)b * NODES_PER_B;
        ebuf[(size_t)(rep * NB + b) * SUBREG + chunkbase + rank] = (dl << 17) | (unsigned)s;
    }
}

// ---------- fuse_enc body: fold encoder into layer-0 weights ----------
__device__ __forceinline__ void fuse_enc_body(const float* __restrict__ We, const float* __restrict__ be,
                                              const float* __restrict__ Wl, const float* __restrict__ bl,
                                              const float* __restrict__ Wr, const float* __restrict__ br,
                                              float* __restrict__ Wcl, float* __restrict__ bcl,
                                              float* __restrict__ Wcr, float* __restrict__ bcr,
                                              float (*sWe)[64], float* sbe) {
    int t = threadIdx.x;
    for (int i = t; i < 4096; i += 256) sWe[i & 63][i >> 6] = We[i];
    if (t < 64) sbe[t] = be[t];
    __syncthreads();
    int j = t & 127, side = t >> 7;
    const float* W  = side ? Wr : Wl;
    const float* bb = side ? br : bl;
    float acc[64];
#pragma unroll
    for (int k = 0; k < 64; ++k) acc[k] = 0.f;
    float bacc = bb[j];
    for (int m = 0; m < 64; ++m) {
        float wv = W[m * 128 + j];
        bacc += sbe[m] * wv;
#pragma unroll
        for (int k = 0; k < 64; ++k) acc[k] += sWe[m][k] * wv;
    }
    float* Wc = side ? Wcr : Wcl;
#pragma unroll
    for (int k = 0; k < 64; ++k) Wc[k * 128 + j] = acc[k];
    (side ? bcr : bcl)[j] = bacc;
}

// ---------- combined: block 0 = fuse_enc, blocks 1.. = bucket_scatter ----------
__global__ __launch_bounds__(256) void scatter_fuse(const int* __restrict__ src, const int* __restrict__ dst,
                                                    int* __restrict__ gcur, unsigned* __restrict__ ebuf,
                                                    const float* __restrict__ We, const float* __restrict__ be,
                                                    const float* __restrict__ Wl, const float* __restrict__ bl,
                                                    const float* __restrict__ Wr, const float* __restrict__ br,
                                                    float* __restrict__ Wcl, float* __restrict__ bcl,
                                                    float* __restrict__ Wcr, float* __restrict__ bcr) {
    __shared__ float sWe[64][64];
    __shared__ float sbe[64];
    if (blockIdx.x == 0)
        fuse_enc_body(We, be, Wl, bl, Wr, br, Wcl, bcl, Wcr, bcr, sWe, sbe);
    else
        bucket_scatter_body(blockIdx.x - 1, src, dst, gcur, ebuf);
}

// ---------- per-layer transforms body, f16 chunks; 2 columns/thread, 16-row tiles ----------
// BN=0: hin is f32 [node][64]; BN=1: hin is f16 [node][64] (u32 pair-packed)
// node chunk k (16B): [h0 c4k..4k+3 | h1 c4k..4k+3], element idx = (c>>2)*8 + head*4 + (c&3)
template <int BN>
__device__ __forceinline__ void layer_gemm_body(int bid, int nb,
                                                const void* __restrict__ hin,
                                                const float* __restrict__ Wl, const float* __restrict__ bl,
                                                const float* __restrict__ Wr, const float* __restrict__ br,
                                                const float* __restrict__ bns, const float* __restrict__ gamma,
                                                const float* __restrict__ beta,
                                                unsigned short* __restrict__ xl, unsigned short* __restrict__ xr,
                                                float* ssc, float* ssh, h2 (*sh)[36]) {
    int t = threadIdx.x;
    if (BN) {
        if (t < 64) {
            float s = 0.f, sq = 0.f;
#pragma unroll
            for (int r = 0; r < 8; ++r) { s += bns[r * 128 + t]; sq += bns[r * 128 + 64 + t]; }
            float mu = s * (1.f / N_NODES);
            float var = sq * (1.f / N_NODES) - mu * mu;
            float sc = gamma[t] * rsqrtf(var + BN_EPS);
            ssc[t] = sc; ssh[t] = beta[t] - mu * sc;
        }
        __syncthreads();
    }
    int p = t & 127, rh = t >> 7;          // column pair, row half
    int col0 = 2 * p;                       // even: col0,col0+1 same side
    bool isR = col0 >= 128;
    int cw0 = col0 & 127, cw1 = cw0 + 1;
    const float* W = isR ? Wr : Wl;
    h2 w2a[32], w2b[32];
#pragma unroll
    for (int k2 = 0; k2 < 32; ++k2) {
        w2a[k2] = (h2){(_Float16)W[(2 * k2) * 128 + cw0], (_Float16)W[(2 * k2 + 1) * 128 + cw0]};
        w2b[k2] = (h2){(_Float16)W[(2 * k2) * 128 + cw1], (_Float16)W[(2 * k2 + 1) * 128 + cw1]};
    }
    float bja = (isR ? br : bl)[cw0];
    float bjb = (isR ? br : bl)[cw1];
    int head0 = cw0 >> 6, c0 = cw0 & 63;
    int head1 = cw1 >> 6, c1 = cw1 & 63;
    int oidx0 = ((c0 >> 2) << 3) + (head0 << 2) + (c0 & 3);
    int oidx1 = ((c1 >> 2) << 3) + (head1 << 2) + (c1 & 3);
    unsigned short* dstp = isR ? xr : xl;
    for (int base = bid * 16; base < N_NODES; base += nb * 16) {
        __syncthreads();
#pragma unroll
        for (int pass = 0; pass < 2; ++pass) {
            int i = t + pass * 256;
            int node = i >> 5, pr = i & 31;
            int gnode = base + node;
            int cc = pr * 2;
            if (BN) {
                unsigned u = (gnode < N_NODES) ? ((const unsigned*)hin)[(size_t)gnode * 32 + pr] : 0u;
                h2 hv = bch2(u);
                float vx = fmaxf((float)hv[0] * ssc[cc] + ssh[cc], 0.f);
                float vy = fmaxf((float)hv[1] * ssc[cc + 1] + ssh[cc + 1], 0.f);
                sh[node][pr] = (h2){(_Float16)vx, (_Float16)vy};
            } else {
                float2 v = make_float2(0.f, 0.f);
                if (gnode < N_NODES) v = *(const float2*)((const float*)hin + (size_t)gnode * 64 + cc);
                sh[node][pr] = (h2){(_Float16)v.x, (_Float16)v.y};
            }
        }
        __syncthreads();
        int lim = min(16, N_NODES - base);
        int rend = min(rh * 8 + 8, lim);
        for (int r = rh * 8; r < rend; ++r) {
            float acca = bja, accb = bjb;
            const uint4* r4 = (const uint4*)(&sh[r][0]);
#pragma unroll
            for (int k4 = 0; k4 < 8; ++k4) {
                uint4 u = r4[k4];
                acca = fdot2f(bch2(u.x), w2a[4 * k4 + 0], acca);
                accb = fdot2f(bch2(u.x), w2b[4 * k4 + 0], accb);
                acca = fdot2f(bch2(u.y), w2a[4 * k4 + 1], acca);
                accb = fdot2f(bch2(u.y), w2b[4 * k4 + 1], accb);
                acca = fdot2f(bch2(u.z), w2a[4 * k4 + 2], acca);
                accb = fdot2f(bch2(u.z), w2b[4 * k4 + 2], accb);
                acca = fdot2f(bch2(u.w), w2a[4 * k4 + 3], acca);
                accb = fdot2f(bch2(u.w), w2b[4 * k4 + 3], accb);
            }
            size_t rowb = (size_t)(base + r) * 128;
            dstp[rowb + oidx0] = __builtin_bit_cast(unsigned short, (_Float16)acca);
            dstp[rowb + oidx1] = __builtin_bit_cast(unsigned short, (_Float16)accb);
        }
    }
}

// ---------- combined: blocks 0..255 = bucket_deg (u8-packed LDS histo, 12.5KB), 256.. = layer_gemm<0> ----------
__global__ __launch_bounds__(256) void deg_gemm0(const int* __restrict__ gcur,
                                                 const unsigned* __restrict__ ebuf,
                                                 int* __restrict__ deg,
                                                 const float* __restrict__ hin,
                                                 const float* __restrict__ Wl, const float* __restrict__ bl,
                                                 const float* __restrict__ Wr, const float* __restrict__ br,
                                                 unsigned short* __restrict__ xl, unsigned short* __restrict__ xr) {
    __shared__ unsigned ldeg4[NODES_PER_B / 4 + 1];   // 12.5 KB: four u8 counts per u32
    __shared__ float ssc[64], ssh[64];
    __shared__ h2 sh[16][36];
    if (blockIdx.x < NREP * NB) {
        int b = blockIdx.x & (NB - 1), rep = blockIdx.x >> 3;
        for (int j = threadIdx.x; j < NODES_PER_B / 4 + 1; j += 256) ldeg4[j] = 0;
        __syncthreads();
        int cnt = gcur[rep * NB + b];
        int base = b * NODES_PER_B;
        const unsigned* p = ebuf + (size_t)(rep * NB + b) * SUBREG;
        for (int i = threadIdx.x; i < cnt; i += 256) {
            unsigned dl = p[i] >> 17;
            atomicAdd(&ldeg4[dl >> 2], 1u << ((dl & 3) * 8));
        }
        __syncthreads();
        for (int j = threadIdx.x; j < NODES_PER_B; j += 256) {
            unsigned v = (ldeg4[j >> 2] >> ((j & 3) * 8)) & 0xffu;
            if (v) atomicAdd(&deg[base + j], (int)v);
        }
    } else {
        layer_gemm_body<0>(blockIdx.x - NREP * NB, 1024, hin, Wl, bl, Wr, br,
                           nullptr, nullptr, nullptr, xl, xr, ssc, ssh, sh);
    }
}

// ---------- bucket_fine (standalone: col scatter needs quiet L2) ----------
__global__ __launch_bounds__(256) void bucket_fine(const int* __restrict__ gcur,
                                                   const unsigned* __restrict__ ebuf,
                                                   int* __restrict__ cursor, int* __restrict__ col) {
    int b = blockIdx.x & (NB - 1), rep = blockIdx.x >> 3;
    int cnt = gcur[rep * NB + b];
    int base = b * NODES_PER_B;
    const unsigned* p = ebuf + (size_t)(rep * NB + b) * SUBREG;
    for (int i = threadIdx.x; i < cnt; i += 256) {
        unsigned e = p[i];
        int d = base + (int)(e >> 17), s = (int)(e & 0x1FFFFu);
        int pos = atomicAdd(&cursor[d], 1);
        col[pos] = s;
    }
}

// ---------- scans for row_ptr (wave-scan) ----------
__global__ void scan_a(const int* __restrict__ deg, int* __restrict__ row_ptr, int* __restrict__ bsum) {
    __shared__ int wsum[16];
    int tid = threadIdx.x;
    int lane = tid & 63;
    int i = blockIdx.x * 1024 + tid;
    int x = (i < N_NODES) ? deg[i] : 0;
#pragma unroll
    for (int o = 1; o < 64; o <<= 1) {
        int y = __shfl_up(x, o, 64);
        if (lane >= o) x += y;
    }
    if (lane == 63) wsum[tid >> 6] = x;
    __syncthreads();
    if (tid < 16) {
        int s = wsum[tid];
#pragma unroll
        for (int o = 1; o < 16; o <<= 1) {
            int y = __shfl_up(s, o, 16);
            if (tid >= o) s += y;
        }
        wsum[tid] = s;
    }
    __syncthreads();
    int pre = (tid >= 64) ? wsum[(tid >> 6) - 1] : 0;
    int incl = x + pre;
    if (i < N_NODES) row_ptr[i + 1] = incl;
    if (tid == 1023) bsum[blockIdx.x] = incl;
}

// scan_c with inline block-sum prefix
__global__ void scan_c(int* __restrict__ cursor, int* __restrict__ row_ptr, const int* __restrict__ bsum) {
    __shared__ int sp[128];
    int t = threadIdx.x;
    if (t < 128) sp[t] = (t < 98) ? bsum[t] : 0;
    __syncthreads();
    for (int o = 1; o < 128; o <<= 1) {
        int v = (t < 128 && t >= o) ? sp[t - o] : 0;
        __syncthreads();
        if (t < 128) sp[t] += v;
        __syncthreads();
    }
    int i = blockIdx.x * 256 + t;
    if (i < N_NODES) {
        int d = cursor[i];
        int blk = i >> 10;
        int pre = blk ? sp[blk - 1] : 0;
        int incl = row_ptr[i + 1] + pre;
        row_ptr[i + 1] = incl;
        cursor[i] = incl - d;           // exclusive start
        if (i == 0) row_ptr[0] = 0;
    }
}

// ---------- standalone layer 1 transform (BN fused, f16 input) ----------
__global__ __launch_bounds__(256) void layer_gemm1(const unsigned short* __restrict__ hin,
                                                   const float* __restrict__ Wl, const float* __restrict__ bl,
                                                   const float* __restrict__ Wr, const float* __restrict__ br,
                                                   const float* __restrict__ bns, const float* __restrict__ gamma,
                                                   const float* __restrict__ beta,
                                                   unsigned short* __restrict__ xl, unsigned short* __restrict__ xr) {
    __shared__ float ssc[64], ssh[64];
    __shared__ h2 sh[16][36];
    layer_gemm_body<1>(blockIdx.x, gridDim.x, hin, Wl, bl, Wr, br, bns, gamma, beta, xl, xr, ssc, ssh, sh);
}

// ---------- fused GATv2 edge phase: att-folded leaky, depth-3 gated prefetch, f16 hn out ----------
__global__ __launch_bounds__(256) void aggregate(const char* __restrict__ xlb,
                                                 const uint4* __restrict__ xr4,
                                                 const int* __restrict__ row_ptr, const int* __restrict__ col,
                                                 const float* __restrict__ att_l, const float* __restrict__ bias_l,
                                                 unsigned short* __restrict__ hn16, float* __restrict__ bnsum) {
    int lane = threadIdx.x & 63, wid = threadIdx.x >> 6;
    int q = lane >> 4, k = lane & 15;
    int koff = k << 4;
    // leaky(z)·att = 0.6·att·z + 0.4·att·|z| — fold 0.6/0.4 into att (f16)
    h2 a6A0 = {(_Float16)(0.6f * att_l[4 * k]), (_Float16)(0.6f * att_l[4 * k + 1])};
    h2 a6A1 = {(_Float16)(0.6f * att_l[4 * k + 2]), (_Float16)(0.6f * att_l[4 * k + 3])};
    h2 a4A0 = {(_Float16)(0.4f * att_l[4 * k]), (_Float16)(0.4f * att_l[4 * k + 1])};
    h2 a4A1 = {(_Float16)(0.4f * att_l[4 * k + 2]), (_Float16)(0.4f * att_l[4 * k + 3])};
    h2 a6B0 = {(_Float16)(0.6f * att_l[64 + 4 * k]), (_Float16)(0.6f * att_l[64 + 4 * k + 1])};
    h2 a6B1 = {(_Float16)(0.6f * att_l[64 + 4 * k + 2]), (_Float16)(0.6f * att_l[64 + 4 * k + 3])};
    h2 a4B0 = {(_Float16)(0.4f * att_l[64 + 4 * k]), (_Float16)(0.4f * att_l[64 + 4 * k + 1])};
    h2 a4B1 = {(_Float16)(0.4f * att_l[64 + 4 * k + 2]), (_Float16)(0.4f * att_l[64 + 4 * k + 3])};
    float bi0 = bias_l[4 * k], bi1 = bias_l[4 * k + 1], bi2 = bias_l[4 * k + 2], bi3 = bias_l[4 * k + 3];
    float ps[4] = {0, 0, 0, 0}, pq[4] = {0, 0, 0, 0};
    int w = blockIdx.x * 4 + wid, nw = gridDim.x * 4;
    for (int v = w; v < N_NODES; v += nw) {
        uint4 rp = xr4[(size_t)v * 16 + k];
        h2 rA0 = bch2(rp.x), rA1 = bch2(rp.y), rB0 = bch2(rp.z), rB1 = bch2(rp.w);
        int beg = row_ptr[v], end = row_ptr[v + 1];
        float s0 = 0.f, s1 = 0.f;
        h2 aA0 = {0, 0}, aA1 = {0, 0}, aB0 = {0, 0}, aB1 = {0, 0};
        const int* cptr = col + beg + q;      // padded: safe to over-read 32 entries
        int cv0 = cptr[0], cv1 = cptr[4], cv2 = cptr[8], cv3 = cptr[12];
        cptr += 16;
        uint4 lp0 = *(const uint4*)(xlb + (((size_t)(unsigned)cv0) << 8) + koff);
        uint4 lp1 = lp0, lp2 = lp0;
        if (beg + 4 < end) lp1 = *(const uint4*)(xlb + (((size_t)(unsigned)cv1) << 8) + koff);
        if (beg + 8 < end) lp2 = *(const uint4*)(xlb + (((size_t)(unsigned)cv2) << 8) + koff);
#pragma unroll 2
        for (int i = beg; i < end; i += 4) {
            uint4 lp3 = lp2;
            if (i + 12 < end) lp3 = *(const uint4*)(xlb + (((size_t)(unsigned)cv3) << 8) + koff);
            cv3 = *cptr; cptr += 4;
            h2 lA0 = bch2(lp0.x), lA1 = bch2(lp0.y), lB0 = bch2(lp0.z), lB1 = bch2(lp0.w);
            h2 zA0 = lA0 + rA0, zA1 = lA1 + rA1, zB0 = lB0 + rB0, zB1 = lB1 + rB1;
            float t0 = fdot2f(habs2(zA1), a4A1, fdot2f(habs2(zA0), a4A0,
                       fdot2f(zA1, a6A1, fdot2f(zA0, a6A0, 0.f))));
            float t1 = fdot2f(habs2(zB1), a4B1, fdot2f(habs2(zB0), a4B0,
                       fdot2f(zB1, a6B1, fdot2f(zB0, a6B0, 0.f))));
            t0 = rowsum16(t0); t1 = rowsum16(t1);
            bool valid = (i + q) < end;
            float p0 = valid ? __expf(t0) : 0.f;
            float p1 = valid ? __expf(t1) : 0.f;
            s0 += p0; s1 += p1;
            h2 p0h = {(_Float16)p0, (_Float16)p0};
            h2 p1h = {(_Float16)p1, (_Float16)p1};
            aA0 += p0h * lA0; aA1 += p0h * lA1;
            aB0 += p1h * lB0; aB1 += p1h * lB1;
            lp0 = lp1; lp1 = lp2; lp2 = lp3;
        }
#pragma unroll
        for (int o = 16; o <= 32; o <<= 1) {
            s0 += __shfl_xor(s0, o, 64); s1 += __shfl_xor(s1, o, 64);
            aA0 += shflx_h2(aA0, o); aA1 += shflx_h2(aA1, o);
            aB0 += shflx_h2(aB0, o); aB1 += shflx_h2(aB1, o);
        }
        if (q == 0) {
            float i0 = 0.5f / s0, i1 = 0.5f / s1;
            float hv0 = (float)aA0[0] * i0 + (float)aB0[0] * i1 + bi0;
            float hv1 = (float)aA0[1] * i0 + (float)aB0[1] * i1 + bi1;
            float hv2 = (float)aA1[0] * i0 + (float)aB1[0] * i1 + bi2;
            float hv3 = (float)aA1[1] * i0 + (float)aB1[1] * i1 + bi3;
            h2 o01 = {(_Float16)hv0, (_Float16)hv1};
            h2 o23 = {(_Float16)hv2, (_Float16)hv3};
            *(uint2*)(hn16 + (size_t)v * 64 + 4 * k) = make_uint2(bcu(o01), bcu(o23));
            ps[0] += hv0; pq[0] += hv0 * hv0;
            ps[1] += hv1; pq[1] += hv1 * hv1;
            ps[2] += hv2; pq[2] += hv2 * hv2;
            ps[3] += hv3; pq[3] += hv3 * hv3;
        }
    }
    __shared__ float sb[2][4][64];
    if (q == 0) {
#pragma unroll
        for (int j = 0; j < 4; ++j) { sb[0][wid][4 * k + j] = ps[j]; sb[1][wid][4 * k + j] = pq[j]; }
    }
    __syncthreads();
    float* dstb = bnsum + (size_t)(blockIdx.x & 7) * 128;
    int t = threadIdx.x;
    if (t < 64)
        atomicAdd(&dstb[t], sb[0][0][t] + sb[0][1][t] + sb[0][2][t] + sb[0][3][t]);
    else if (t < 128)
        atomicAdd(&dstb[t], sb[1][0][t - 64] + sb[1][1][t - 64] + sb[1][2][t - 64] + sb[1][3][t - 64]);
}

// ---------- pool (f16 hn, BN fused) + classifier (last-block) ----------
__global__ __launch_bounds__(256) void pool_cls(const unsigned short* __restrict__ hn,
                                                const int* __restrict__ batch,
                                                const float* __restrict__ bns, const float* __restrict__ gamma,
                                                const float* __restrict__ beta,
                                                const float* __restrict__ Wc, const float* __restrict__ bcb,
                                                float* __restrict__ gpool, float* __restrict__ gcnt,
                                                int* __restrict__ pcount, float* __restrict__ out) {
    __shared__ float ssc[64], ssh[64];
    __shared__ int lastf;
    int t = threadIdx.x;
    if (t < 64) {
        float s = 0.f, sq = 0.f;
#pragma unroll
        for (int r = 0; r < 8; ++r) { s += bns[r * 128 + t]; sq += bns[r * 128 + 64 + t]; }
        float mu = s * (1.f / N_NODES);
        float var = sq * (1.f / N_NODES) - mu * mu;
        float sc = gamma[t] * rsqrtf(var + BN_EPS);
        ssc[t] = sc; ssh[t] = beta[t] - mu * sc;
    }
    __syncthreads();
    int g = blockIdx.x >> 2, part = blockIdx.x & 3;
    int lo = 0, hi = N_NODES;
    while (lo < hi) { int mid = (lo + hi) >> 1; if (batch[mid] < g) lo = mid + 1; else hi = mid; }
    int lo2 = lo, hi2 = N_NODES;
    while (lo2 < hi2) { int mid = (lo2 + hi2) >> 1; if (batch[mid] < g + 1) lo2 = mid + 1; else hi2 = mid; }
    int len = lo2 - lo;
    if (part == 0 && t == 0) gcnt[g] = (float)len;
    int n0 = lo + (len * part) / 4, n1 = lo + (len * (part + 1)) / 4;
    int c = t & 63, r = t >> 6;
    float sc = ssc[c], sh = ssh[c];
    float acc = 0.f;
    for (int node = n0 + r; node < n1; node += 4) {
        float hv = (float)__builtin_bit_cast(_Float16, hn[(size_t)node * 64 + c]);
        acc += fmaxf(hv * sc + sh, 0.f);
    }
    __shared__ float sb[4][64];
    sb[r][c] = acc;
    __syncthreads();
    if (r == 0)
        atomicAdd(&gpool[g * 64 + c], sb[0][c] + sb[1][c] + sb[2][c] + sb[3][c]);
    __threadfence();
    __syncthreads();
    if (t == 0) lastf = (atomicAdd(pcount, 1) == (int)gridDim.x - 1);
    __syncthreads();
    if (lastf) {
        __threadfence();
        for (int i = t; i < 640; i += 256) {
            int b = i / 10, o = i % 10;
            float inv = 1.f / fmaxf(gcnt[b], 1.f);
            float a = 0.f;
            for (int cc = 0; cc < 64; ++cc) a += gpool[b * 64 + cc] * Wc[cc * 10 + o];
            out[i] = a * inv + bcb[o];
        }
    }
}

extern "C" void kernel_launch(void* const* d_in, const int* in_sizes, int n_in,
                              void* d_out, int out_size, void* d_ws, size_t ws_size,
                              hipStream_t stream) {
    (void)in_sizes; (void)n_in; (void)out_size; (void)ws_size;
    const float* x     = (const float*)d_in[0];
    const int*   ei    = (const int*)d_in[1];
    const int*   batch = (const int*)d_in[2];
    const float* W_enc = (const float*)d_in[3];
    const float* b_enc = (const float*)d_in[4];
    const float* Wl    = (const float*)d_in[5];
    const float* bl    = (const float*)d_in[6];
    const float* Wr    = (const float*)d_in[7];
    const float* br    = (const float*)d_in[8];
    const float* att   = (const float*)d_in[9];
    const float* bias  = (const float*)d_in[10];
    const float* gamma = (const float*)d_in[11];
    const float* beta  = (const float*)d_in[12];
    const float* Wc    = (const float*)d_in[13];
    const float* bc    = (const float*)d_in[14];
    float* out = (float*)d_out;

    char* ws = (char*)d_ws;
    size_t off = 0;
    auto A = [&](size_t bytes) { size_t r = off; off += (bytes + 255) & ~(size_t)255; return r; };

    int* row_ptr = (int*)(ws + A((N_NODES + 1) * 4));
    // colv followed immediately by the contiguous zero region (one memset)
    size_t colv_off = A((size_t)EP_EDGES * 4 + 426496);
    int* colv = (int*)(ws + colv_off);
    char* zbase = ws + colv_off + (size_t)EP_EDGES * 4;
    int*   cursor = (int*)(zbase + 128);              // 400000 B  (col pad = zbase+0, 128 B)
    int*   gcur   = (int*)(zbase + 400128);           // 1024 B
    float* bns    = (float*)(zbase + 401152);         // 8192 B (2 layers x 8 reps x 128)
    float* gpool  = (float*)(zbase + 409344);         // 16384 B
    float* gcnt   = (float*)(zbase + 425728);         // 256 B
    int*   pcount = (int*)(zbase + 425984);           // 256 B
    const size_t ZBYTES = 426496;

    unsigned short* hn = (unsigned short*)(ws + A((size_t)N_NODES * 64 * 2));   // f16 [N][64]
    unsigned short* h2buf = (unsigned short*)(ws + A((size_t)N_NODES * 64 * 2)); // f16 [N][64]
    unsigned short* xl = (unsigned short*)(ws + A((size_t)N_NODES * 128 * 2));
    unsigned short* xr = (unsigned short*)(ws + A((size_t)N_NODES * 128 * 2));
    unsigned* ebuf = (unsigned*)(ws + A((size_t)NREP * NB * SUBREG * 4));
    int* bsum  = (int*)(ws + A(512));
    float* Wcl = (float*)(ws + A(64 * 128 * 4));
    float* Wcr = (float*)(ws + A(64 * 128 * 4));
    float* bcl = (float*)(ws + A(128 * 4));
    float* bcr = (float*)(ws + A(128 * 4));

    const int* srcv = ei;
    const int* dstv = ei + E_EDGES;

    hipMemsetAsync(zbase, 0, ZBYTES, stream);

    // bucket_scatter ∥ fuse_enc
    scatter_fuse<<<SCATTER_BLKS + 1, 256, 0, stream>>>(srcv, dstv, gcur, ebuf,
                                                       W_enc, b_enc, Wl, bl, Wr, br,
                                                       Wcl, bcl, Wcr, bcr);
    // bucket_deg ∥ layer_gemm<0> (deg LDS now 12.5 KB: gemm side keeps occupancy)
    deg_gemm0<<<NREP * NB + 1024, 256, 0, stream>>>(gcur, ebuf, cursor,
                                                    x, Wcl, bcl, Wcr, bcr, xl, xr);
    scan_a<<<98, 1024, 0, stream>>>(cursor, row_ptr, bsum);
    scan_c<<<(N_NODES + 255) / 256, 256, 0, stream>>>(cursor, row_ptr, bsum);
    bucket_fine<<<NREP * NB, 256, 0, stream>>>(gcur, ebuf, cursor, colv);

    aggregate<<<4096, 256, 0, stream>>>((const char*)xl, (const uint4*)xr,
                                        row_ptr, colv, att, bias, hn, bns);
    // layer 1 (BN of layer 0 folded into prologue, f16 input)
    layer_gemm1<<<1024, 256, 0, stream>>>(hn, Wl + 64 * 128, bl + 128, Wr + 64 * 128, br + 128,
                                          bns, gamma, beta, xl, xr);
    aggregate<<<4096, 256, 0, stream>>>((const char*)xl, (const uint4*)xr,
                                        row_ptr, colv, att + 128, bias + 64, h2buf, bns + 1024);

    // pool (BN of layer 1 fused, f16 input) + classifier
    pool_cls<<<256, 256, 0, stream>>>(h2buf, batch, bns + 1024, gamma + 64, beta + 64,
                                      Wc, bc, gpool, gcnt, pcount, out);
}

// Round 13
// 365.413 us; speedup vs baseline: 1.2388x; 1.2388x over previous
//
#include <hip/hip_runtime.h>

#define N_NODES 100000
#define E_EDGES 1600000
#define EP_EDGES (E_EDGES + N_NODES)   // 1,700,000 with self loops
#define SLOPE 0.2f
#define BN_EPS 1e-5f
#define NB 8                 // dst buckets (one per XCD)
#define NODES_PER_B 12500
#define NREP 32              // sub-region replicas per bucket
#define SUBREG 8192          // edges per (rep,bucket) sub-region
#define SCATTER_BLKS ((EP_EDGES + 255) / 256)
#define NBLK ((N_NODES + 63) / 64)     // 1563 mfma tiles

typedef _Float16 h2 __attribute__((ext_vector_type(2)));
typedef _Float16 v4h __attribute__((ext_vector_type(4)));
typedef _Float16 v8h __attribute__((ext_vector_type(8)));
typedef float v4f __attribute__((ext_vector_type(4)));

#if defined(__has_builtin)
#if __has_builtin(__builtin_amdgcn_fdot2)
#define HAVE_FDOT2 1
#endif
#endif

__device__ __forceinline__ float fdot2f(h2 a, h2 b, float c) {
#ifdef HAVE_FDOT2
    return __builtin_amdgcn_fdot2(a, b, c, false);
#else
    return c + (float)a[0] * (float)b[0] + (float)a[1] * (float)b[1];
#endif
}
__device__ __forceinline__ h2 bch2(unsigned u) { return __builtin_bit_cast(h2, u); }
__device__ __forceinline__ unsigned bcu(h2 v) { return __builtin_bit_cast(unsigned, v); }
__device__ __forceinline__ h2 habs2(h2 z) {
    return __builtin_bit_cast(h2, (unsigned)(__builtin_bit_cast(unsigned, z) & 0x7fff7fffu));
}
__device__ __forceinline__ h2 shflx_h2(h2 a, int o) {
    return __builtin_bit_cast(h2, __shfl_xor(__builtin_bit_cast(int, a), o, 64));
}

// DPP rotate-reduce: sum across each 16-lane row, pure VALU
template <int CTRL>
__device__ __forceinline__ float dpp_add_step(float v) {
    int r = __builtin_amdgcn_update_dpp(0, __float_as_int(v), CTRL, 0xF, 0xF, false);
    return v + __int_as_float(r);
}
__device__ __forceinline__ float rowsum16(float v) {
    v = dpp_add_step<0x128>(v);
    v = dpp_add_step<0x124>(v);
    v = dpp_add_step<0x122>(v);
    v = dpp_add_step<0x121>(v);
    return v;
}

// ---------- bucket_scatter body (u32-packed edges: (dlocal<<17)|src) ----------
__device__ __forceinline__ void bucket_scatter_body(int bid, const int* __restrict__ src,
                                                    const int* __restrict__ dst,
                                                    int* __restrict__ gcur, unsigned* __restrict__ ebuf) {
    int i = bid * 256 + threadIdx.x;
    int rep = bid & (NREP - 1);
    bool active = i < EP_EDGES;
    int s = 0, d = 0;
    if (i < E_EDGES) { s = src[i]; d = dst[i]; }
    else if (active) { s = i - E_EDGES; d = s; }
    int b = active ? (int)((unsigned)d / NODES_PER_B) : NB;
    unsigned long long lt = (1ull << (threadIdx.x & 63)) - 1ull;
    int rank = 0;
    unsigned long long mymask = 0;
#pragma unroll
    for (int bb = 0; bb < NB; ++bb) {
        unsigned long long m = __ballot(b == bb);
        if (b == bb) { rank = __popcll(m & lt); mymask = m; }
    }
    int leader = mymask ? (__ffsll((long long)mymask) - 1) : 0;
    int lanebit = threadIdx.x & 63;
    int chunkbase = 0;
    if (active && lanebit == leader)
        chunkbase = atomicAdd(&gcur[rep * NB + b], (int)__popcll(mymask));
    chunkbase = __shfl(chunkbase, leader, 64);
    if (active) {
        unsigned dl = (unsigned)d - (unsigned)b * NODES_PER_B;
        ebuf[(size_t)(rep * NB + b) * SUBREG + chunkbase + rank] = (dl << 17) | (unsigned)s;
    }
}

// ---------- block 0: fuse encoder into layer-0 weights, pack MFMA B-frags directly ----------
__device__ __forceinline__ void fuse_enc_pack0(const float* __restrict__ We, const float* __restrict__ be,
                                               const float* __restrict__ Wl, const float* __restrict__ bl,
                                               const float* __restrict__ Wr, const float* __restrict__ br,
                                               _Float16* __restrict__ Wfrag0, float* __restrict__ bias0,
                                               float (*sWe)[64], float* sbe) {
    int t = threadIdx.x;
    for (int i = t; i < 4096; i += 256) sWe[i & 63][i >> 6] = We[i];
    if (t < 64) sbe[t] = be[t];
    __syncthreads();
    int j = t & 127, side = t >> 7;
    const float* W  = side ? Wr : Wl;
    const float* bb = side ? br : bl;
    float acc[64];
#pragma unroll
    for (int k = 0; k < 64; ++k) acc[k] = 0.f;
    float bacc = bb[j];
    for (int m = 0; m < 64; ++m) {
        float wv = W[m * 128 + j];
        bacc += sbe[m] * wv;
#pragma unroll
        for (int k = 0; k < 64; ++k) acc[k] += sWe[m][k] * wv;
    }
    int ncolg = (side << 7) | j;
    int w = ncolg >> 6, nt = (ncolg >> 4) & 3, lp = ncolg & 15;
#pragma unroll
    for (int k = 0; k < 64; ++k) {
        int kt = k >> 5;
        int l = (((k >> 3) & 3) << 4) | lp;
        int jj = k & 7;
        Wfrag0[((((w * 4 + nt) * 2 + kt)) << 9) + (l << 3) + jj] = (_Float16)acc[k];
    }
    bias0[ncolg] = bacc;
}

// ---------- block 1: pack layer-1 weights into MFMA B-frag order ----------
__device__ __forceinline__ void pack1_body(const float* __restrict__ WL, const float* __restrict__ WR,
                                           const float* __restrict__ bL, const float* __restrict__ bR,
                                           _Float16* __restrict__ Wfrag, float* __restrict__ bias_all) {
    int t = threadIdx.x;
    for (int i = t; i < 16384; i += 256) {
        int j = i & 7, l = (i >> 3) & 63, kt = (i >> 9) & 1, nt = (i >> 10) & 3, w = i >> 12;
        int ncol = w * 64 + nt * 16 + (l & 15);
        int k = kt * 32 + (l >> 4) * 8 + j;
        int side = ncol >> 7, colW = ncol & 127;
        Wfrag[i] = (_Float16)((side ? WR : WL)[k * 128 + colW]);
    }
    if (t < 256) {
        int side = t >> 7, colW = t & 127;
        bias_all[t] = (side ? bR : bL)[colW];
    }
}

// ---------- combined: block 0 = fuse_enc+pack0, block 1 = pack1, blocks 2.. = bucket_scatter ----------
__global__ __launch_bounds__(256) void scatter_fuse(const int* __restrict__ src, const int* __restrict__ dst,
                                                    int* __restrict__ gcur, unsigned* __restrict__ ebuf,
                                                    const float* __restrict__ We, const float* __restrict__ be,
                                                    const float* __restrict__ Wl, const float* __restrict__ bl,
                                                    const float* __restrict__ Wr, const float* __restrict__ br,
                                                    _Float16* __restrict__ Wfrag0, float* __restrict__ bias0,
                                                    _Float16* __restrict__ Wfrag1, float* __restrict__ bias1) {
    __shared__ float sWe[64][64];
    __shared__ float sbe[64];
    if (blockIdx.x == 0)
        fuse_enc_pack0(We, be, Wl, bl, Wr, br, Wfrag0, bias0, sWe, sbe);
    else if (blockIdx.x == 1)
        pack1_body(Wl + 64 * 128, Wr + 64 * 128, bl + 128, br + 128, Wfrag1, bias1);
    else
        bucket_scatter_body(blockIdx.x - 2, src, dst, gcur, ebuf);
}

// ---------- MFMA layer transform body: 64 nodes x 256 cols per block ----------
// sA: 64x64 f16, 16B-chunk XOR swizzle: addr16 = (node*128 + chunk*16) ^ ((node&7)<<4)
// BN=0: hin f32 [N][64]; BN=1: hin f16 [N][64] with BN+ReLU fused
template <int BN>
__device__ __forceinline__ void mfma_body(int mb, const void* __restrict__ hin,
                                          const _Float16* __restrict__ Wfrag,
                                          const float* __restrict__ bias_all,
                                          const float* __restrict__ bns, const float* __restrict__ gamma,
                                          const float* __restrict__ beta,
                                          unsigned short* __restrict__ xl, unsigned short* __restrict__ xr,
                                          char* smem, float* ssc, float* ssh) {
    int t = threadIdx.x;
    int w = t >> 6, l = t & 63;
    if (BN) {
        if (t < 64) {
            float s = 0.f, sq = 0.f;
#pragma unroll
            for (int r = 0; r < 8; ++r) { s += bns[r * 128 + t]; sq += bns[r * 128 + 64 + t]; }
            float mu = s * (1.f / N_NODES);
            float var = sq * (1.f / N_NODES) - mu * mu;
            float sc = gamma[t] * rsqrtf(var + BN_EPS);
            ssc[t] = sc; ssh[t] = beta[t] - mu * sc;
        }
        __syncthreads();
    }
    int base = mb * 64;
    if (BN == 0) {
#pragma unroll
        for (int pass = 0; pass < 4; ++pass) {
            int idx = t + pass * 256;
            int node = idx >> 4, q4 = idx & 15;
            int gnode = base + node;
            float4 v = make_float4(0.f, 0.f, 0.f, 0.f);
            if (gnode < N_NODES) v = *(const float4*)((const float*)hin + (size_t)gnode * 64 + q4 * 4);
            v4h p = {(_Float16)v.x, (_Float16)v.y, (_Float16)v.z, (_Float16)v.w};
            int byte = (node * 128 + q4 * 8) ^ ((node & 7) << 4);
            *(v4h*)(smem + byte) = p;
        }
    } else {
#pragma unroll
        for (int pass = 0; pass < 2; ++pass) {
            int idx = t + pass * 256;
            int node = idx >> 3, q8 = idx & 7;
            int gnode = base + node;
            uint4 u = make_uint4(0, 0, 0, 0);
            if (gnode < N_NODES) u = *(const uint4*)((const unsigned short*)hin + (size_t)gnode * 64 + q8 * 8);
            int c0 = q8 * 8;
            h2 p0 = bch2(u.x), p1 = bch2(u.y), p2 = bch2(u.z), p3 = bch2(u.w);
            float a, b;
            a = fmaxf((float)p0[0] * ssc[c0 + 0] + ssh[c0 + 0], 0.f);
            b = fmaxf((float)p0[1] * ssc[c0 + 1] + ssh[c0 + 1], 0.f);
            p0 = (h2){(_Float16)a, (_Float16)b};
            a = fmaxf((float)p1[0] * ssc[c0 + 2] + ssh[c0 + 2], 0.f);
            b = fmaxf((float)p1[1] * ssc[c0 + 3] + ssh[c0 + 3], 0.f);
            p1 = (h2){(_Float16)a, (_Float16)b};
            a = fmaxf((float)p2[0] * ssc[c0 + 4] + ssh[c0 + 4], 0.f);
            b = fmaxf((float)p2[1] * ssc[c0 + 5] + ssh[c0 + 5], 0.f);
            p2 = (h2){(_Float16)a, (_Float16)b};
            a = fmaxf((float)p3[0] * ssc[c0 + 6] + ssh[c0 + 6], 0.f);
            b = fmaxf((float)p3[1] * ssc[c0 + 7] + ssh[c0 + 7], 0.f);
            p3 = (h2){(_Float16)a, (_Float16)b};
            int byte = (node * 128 + q8 * 16) ^ ((node & 7) << 4);
            *(uint4*)(smem + byte) = make_uint4(bcu(p0), bcu(p1), bcu(p2), bcu(p3));
        }
    }
    // B fragments -> registers
    v8h bfr[4][2];
    float biasv[4];
#pragma unroll
    for (int nt = 0; nt < 4; ++nt) {
#pragma unroll
        for (int kt = 0; kt < 2; ++kt)
            bfr[nt][kt] = *(const v8h*)(Wfrag + ((((w * 4 + nt) * 2 + kt) << 9) + (l << 3)));
        biasv[nt] = bias_all[w * 64 + nt * 16 + (l & 15)];
    }
    __syncthreads();
    v4f acc[4][4];
#pragma unroll
    for (int mt = 0; mt < 4; ++mt)
#pragma unroll
        for (int nt = 0; nt < 4; ++nt)
            acc[mt][nt] = (v4f){0.f, 0.f, 0.f, 0.f};
#pragma unroll
    for (int mt = 0; mt < 4; ++mt) {
        int node = mt * 16 + (l & 15);
        int swz = (node & 7) << 4;
        int b0 = (node * 128 + ((l >> 4) << 4)) ^ swz;
        int b1 = (node * 128 + 64 + ((l >> 4) << 4)) ^ swz;   // FIX: XOR after +64
        v8h a0 = *(const v8h*)(smem + b0);
        v8h a1 = *(const v8h*)(smem + b1);
#pragma unroll
        for (int nt = 0; nt < 4; ++nt) {
            acc[mt][nt] = __builtin_amdgcn_mfma_f32_16x16x32_f16(a0, bfr[nt][0], acc[mt][nt], 0, 0, 0);
            acc[mt][nt] = __builtin_amdgcn_mfma_f32_16x16x32_f16(a1, bfr[nt][1], acc[mt][nt], 0, 0, 0);
        }
    }
    // epilogue: bias, f16, transpose through LDS into chunk format
    _Float16* sOut = (_Float16*)(smem + 8192);
    __syncthreads();
#pragma unroll
    for (int mt = 0; mt < 4; ++mt) {
#pragma unroll
        for (int nt = 0; nt < 4; ++nt) {
            int ncol = (w << 6) + (nt << 4) + (l & 15);
            int side = ncol >> 7, head = (ncol >> 6) & 1, c = ncol & 63;
            int oidx = ((c >> 2) << 3) + (head << 2) + (c & 3);
            int obase = side * 128 + oidx;
#pragma unroll
            for (int j = 0; j < 4; ++j) {
                int node = mt * 16 + ((l >> 4) << 2) + j;
                sOut[node * 256 + obase] = (_Float16)(acc[mt][nt][j] + biasv[nt]);
            }
        }
    }
    __syncthreads();
#pragma unroll
    for (int pass = 0; pass < 8; ++pass) {
        int idx = t + pass * 256;
        int node = idx >> 5, wi = idx & 31;
        int gnode = base + node;
        if (gnode < N_NODES) {
            int side = wi >> 4, o16 = wi & 15;
            uint4 val = *(const uint4*)(sOut + node * 256 + side * 128 + o16 * 8);
            unsigned short* dstp = side ? xr : xl;
            *(uint4*)(dstp + (size_t)gnode * 128 + o16 * 8) = val;
        }
    }
}

// ---------- combined: blocks 0..255 = bucket_deg (u8 LDS histo), 256.. = mfma layer 0 ----------
__global__ __launch_bounds__(256) void deg_mfma0(const int* __restrict__ gcur,
                                                 const unsigned* __restrict__ ebuf,
                                                 int* __restrict__ deg,
                                                 const float* __restrict__ x,
                                                 const _Float16* __restrict__ Wfrag0,
                                                 const float* __restrict__ bias0,
                                                 unsigned short* __restrict__ xl, unsigned short* __restrict__ xr) {
    __shared__ __align__(16) char smem[40960];
    __shared__ float ssc[64], ssh[64];
    if (blockIdx.x < NREP * NB) {
        unsigned* ldeg4 = (unsigned*)smem;                 // 12.5 KB: four u8 counts per u32
        int b = blockIdx.x & (NB - 1), rep = blockIdx.x >> 3;
        for (int j = threadIdx.x; j < NODES_PER_B / 4 + 1; j += 256) ldeg4[j] = 0;
        __syncthreads();
        int cnt = gcur[rep * NB + b];
        int base = b * NODES_PER_B;
        const unsigned* p = ebuf + (size_t)(rep * NB + b) * SUBREG;
        for (int i = threadIdx.x; i < cnt; i += 256) {
            unsigned dl = p[i] >> 17;
            atomicAdd(&ldeg4[dl >> 2], 1u << ((dl & 3) * 8));
        }
        __syncthreads();
        for (int j = threadIdx.x; j < NODES_PER_B; j += 256) {
            unsigned v = (ldeg4[j >> 2] >> ((j & 3) * 8)) & 0xffu;
            if (v) atomicAdd(&deg[base + j], (int)v);
        }
    } else {
        mfma_body<0>(blockIdx.x - NREP * NB, x, Wfrag0, bias0, nullptr, nullptr, nullptr,
                     xl, xr, smem, ssc, ssh);
    }
}

// ---------- standalone mfma layer 1 (BN fused, f16 input) ----------
__global__ __launch_bounds__(256) void mfma1(const unsigned short* __restrict__ hin,
                                             const _Float16* __restrict__ Wfrag1,
                                             const float* __restrict__ bias1,
                                             const float* __restrict__ bns, const float* __restrict__ gamma,
                                             const float* __restrict__ beta,
                                             unsigned short* __restrict__ xl, unsigned short* __restrict__ xr) {
    __shared__ __align__(16) char smem[40960];
    __shared__ float ssc[64], ssh[64];
    mfma_body<1>(blockIdx.x, hin, Wfrag1, bias1, bns, gamma, beta, xl, xr, smem, ssc, ssh);
}

// ---------- bucket_fine (standalone: col scatter needs quiet L2) ----------
__global__ __launch_bounds__(256) void bucket_fine(const int* __restrict__ gcur,
                                                   const unsigned* __restrict__ ebuf,
                                                   int* __restrict__ cursor, int* __restrict__ col) {
    int b = blockIdx.x & (NB - 1), rep = blockIdx.x >> 3;
    int cnt = gcur[rep * NB + b];
    int base = b * NODES_PER_B;
    const unsigned* p = ebuf + (size_t)(rep * NB + b) * SUBREG;
    for (int i = threadIdx.x; i < cnt; i += 256) {
        unsigned e = p[i];
        int d = base + (int)(e >> 17), s = (int)(e & 0x1FFFFu);
        int pos = atomicAdd(&cursor[d], 1);
        col[pos] = s;
    }
}

// ---------- scans for row_ptr (wave-scan) ----------
__global__ void scan_a(const int* __restrict__ deg, int* __restrict__ row_ptr, int* __restrict__ bsum) {
    __shared__ int wsum[16];
    int tid = threadIdx.x;
    int lane = tid & 63;
    int i = blockIdx.x * 1024 + tid;
    int x = (i < N_NODES) ? deg[i] : 0;
#pragma unroll
    for (int o = 1; o < 64; o <<= 1) {
        int y = __shfl_up(x, o, 64);
        if (lane >= o) x += y;
    }
    if (lane == 63) wsum[tid >> 6] = x;
    __syncthreads();
    if (tid < 16) {
        int s = wsum[tid];
#pragma unroll
        for (int o = 1; o < 16; o <<= 1) {
            int y = __shfl_up(s, o, 16);
            if (tid >= o) s += y;
        }
        wsum[tid] = s;
    }
    __syncthreads();
    int pre = (tid >= 64) ? wsum[(tid >> 6) - 1] : 0;
    int incl = x + pre;
    if (i < N_NODES) row_ptr[i + 1] = incl;
    if (tid == 1023) bsum[blockIdx.x] = incl;
}

// scan_c with inline block-sum prefix
__global__ void scan_c(int* __restrict__ cursor, int* __restrict__ row_ptr, const int* __restrict__ bsum) {
    __shared__ int sp[128];
    int t = threadIdx.x;
    if (t < 128) sp[t] = (t < 98) ? bsum[t] : 0;
    __syncthreads();
    for (int o = 1; o < 128; o <<= 1) {
        int v = (t < 128 && t >= o) ? sp[t - o] : 0;
        __syncthreads();
        if (t < 128) sp[t] += v;
        __syncthreads();
    }
    int i = blockIdx.x * 256 + t;
    if (i < N_NODES) {
        int d = cursor[i];
        int blk = i >> 10;
        int pre = blk ? sp[blk - 1] : 0;
        int incl = row_ptr[i + 1] + pre;
        row_ptr[i + 1] = incl;
        cursor[i] = incl - d;           // exclusive start
        if (i == 0) row_ptr[0] = 0;
    }
}

// ---------- fused GATv2 edge phase: packed-f16, depth-3 gated prefetch, f16 hn out ----------
__global__ __launch_bounds__(256) void aggregate(const char* __restrict__ xlb,
                                                 const uint4* __restrict__ xr4,
                                                 const int* __restrict__ row_ptr, const int* __restrict__ col,
                                                 const float* __restrict__ att_l, const float* __restrict__ bias_l,
                                                 unsigned short* __restrict__ hn16, float* __restrict__ bnsum) {
    int lane = threadIdx.x & 63, wid = threadIdx.x >> 6;
    int q = lane >> 4, k = lane & 15;
    int koff = k << 4;
    h2 atA0 = {(_Float16)att_l[4 * k], (_Float16)att_l[4 * k + 1]};
    h2 atA1 = {(_Float16)att_l[4 * k + 2], (_Float16)att_l[4 * k + 3]};
    h2 atB0 = {(_Float16)att_l[64 + 4 * k], (_Float16)att_l[64 + 4 * k + 1]};
    h2 atB1 = {(_Float16)att_l[64 + 4 * k + 2], (_Float16)att_l[64 + 4 * k + 3]};
    float bi0 = bias_l[4 * k], bi1 = bias_l[4 * k + 1], bi2 = bias_l[4 * k + 2], bi3 = bias_l[4 * k + 3];
    const h2 c06 = {(_Float16)0.6f, (_Float16)0.6f};
    const h2 c04 = {(_Float16)0.4f, (_Float16)0.4f};
    float ps[4] = {0, 0, 0, 0}, pq[4] = {0, 0, 0, 0};
    int w = blockIdx.x * 4 + wid, nw = gridDim.x * 4;
    for (int v = w; v < N_NODES; v += nw) {
        uint4 rp = xr4[(size_t)v * 16 + k];
        h2 rA0 = bch2(rp.x), rA1 = bch2(rp.y), rB0 = bch2(rp.z), rB1 = bch2(rp.w);
        int beg = row_ptr[v], end = row_ptr[v + 1];
        float s0 = 0.f, s1 = 0.f;
        h2 aA0 = {0, 0}, aA1 = {0, 0}, aB0 = {0, 0}, aB1 = {0, 0};
        const int* cptr = col + beg + q;      // padded: safe to over-read 32 entries
        int cv0 = cptr[0], cv1 = cptr[4], cv2 = cptr[8], cv3 = cptr[12];
        cptr += 16;
        uint4 lp0 = *(const uint4*)(xlb + (((size_t)(unsigned)cv0) << 8) + koff);
        uint4 lp1 = lp0, lp2 = lp0;
        if (beg + 4 < end) lp1 = *(const uint4*)(xlb + (((size_t)(unsigned)cv1) << 8) + koff);
        if (beg + 8 < end) lp2 = *(const uint4*)(xlb + (((size_t)(unsigned)cv2) << 8) + koff);
#pragma unroll 2
        for (int i = beg; i < end; i += 4) {
            uint4 lp3 = lp2;
            if (i + 12 < end) lp3 = *(const uint4*)(xlb + (((size_t)(unsigned)cv3) << 8) + koff);
            cv3 = *cptr; cptr += 4;
            h2 lA0 = bch2(lp0.x), lA1 = bch2(lp0.y), lB0 = bch2(lp0.z), lB1 = bch2(lp0.w);
            h2 zA0 = lA0 + rA0, zA1 = lA1 + rA1, zB0 = lB0 + rB0, zB1 = lB1 + rB1;
            h2 yA0 = zA0 * c06 + habs2(zA0) * c04;
            h2 yA1 = zA1 * c06 + habs2(zA1) * c04;
            h2 yB0 = zB0 * c06 + habs2(zB0) * c04;
            h2 yB1 = zB1 * c06 + habs2(zB1) * c04;
            float t0 = fdot2f(yA1, atA1, fdot2f(yA0, atA0, 0.f));
            float t1 = fdot2f(yB1, atB1, fdot2f(yB0, atB0, 0.f));
            t0 = rowsum16(t0); t1 = rowsum16(t1);
            bool valid = (i + q) < end;
            float p0 = valid ? __expf(t0) : 0.f;
            float p1 = valid ? __expf(t1) : 0.f;
            s0 += p0; s1 += p1;
            h2 p0h = {(_Float16)p0, (_Float16)p0};
            h2 p1h = {(_Float16)p1, (_Float16)p1};
            aA0 += p0h * lA0; aA1 += p0h * lA1;
            aB0 += p1h * lB0; aB1 += p1h * lB1;
            lp0 = lp1; lp1 = lp2; lp2 = lp3;
        }
#pragma unroll
        for (int o = 16; o <= 32; o <<= 1) {
            s0 += __shfl_xor(s0, o, 64); s1 += __shfl_xor(s1, o, 64);
            aA0 += shflx_h2(aA0, o); aA1 += shflx_h2(aA1, o);
            aB0 += shflx_h2(aB0, o); aB1 += shflx_h2(aB1, o);
        }
        if (q == 0) {
            float i0 = 0.5f / s0, i1 = 0.5f / s1;
            float hv0 = (float)aA0[0] * i0 + (float)aB0[0] * i1 + bi0;
            float hv1 = (float)aA0[1] * i0 + (float)aB0[1] * i1 + bi1;
            float hv2 = (float)aA1[0] * i0 + (float)aB1[0] * i1 + bi2;
            float hv3 = (float)aA1[1] * i0 + (float)aB1[1] * i1 + bi3;
            h2 o01 = {(_Float16)hv0, (_Float16)hv1};
            h2 o23 = {(_Float16)hv2, (_Float16)hv3};
            *(uint2*)(hn16 + (size_t)v * 64 + 4 * k) = make_uint2(bcu(o01), bcu(o23));
            ps[0] += hv0; pq[0] += hv0 * hv0;
            ps[1] += hv1; pq[1] += hv1 * hv1;
            ps[2] += hv2; pq[2] += hv2 * hv2;
            ps[3] += hv3; pq[3] += hv3 * hv3;
        }
    }
    __shared__ float sb[2][4][64];
    if (q == 0) {
#pragma unroll
        for (int j = 0; j < 4; ++j) { sb[0][wid][4 * k + j] = ps[j]; sb[1][wid][4 * k + j] = pq[j]; }
    }
    __syncthreads();
    float* dstb = bnsum + (size_t)(blockIdx.x & 7) * 128;
    int t = threadIdx.x;
    if (t < 64)
        atomicAdd(&dstb[t], sb[0][0][t] + sb[0][1][t] + sb[0][2][t] + sb[0][3][t]);
    else if (t < 128)
        atomicAdd(&dstb[t], sb[1][0][t - 64] + sb[1][1][t - 64] + sb[1][2][t - 64] + sb[1][3][t - 64]);
}

// ---------- pool: per-graph blocks via binary search; BN fused; f16 input ----------
__global__ __launch_bounds__(256) void pool2(const unsigned short* __restrict__ hn,
                                             const int* __restrict__ batch,
                                             const float* __restrict__ bns, const float* __restrict__ gamma,
                                             const float* __restrict__ beta,
                                             float* __restrict__ gpool, float* __restrict__ gcnt) {
    __shared__ float ssc[64], ssh[64];
    int t = threadIdx.x;
    if (t < 64) {
        float s = 0.f, sq = 0.f;
#pragma unroll
        for (int r = 0; r < 8; ++r) { s += bns[r * 128 + t]; sq += bns[r * 128 + 64 + t]; }
        float mu = s * (1.f / N_NODES);
        float var = sq * (1.f / N_NODES) - mu * mu;
        float sc = gamma[t] * rsqrtf(var + BN_EPS);
        ssc[t] = sc; ssh[t] = beta[t] - mu * sc;
    }
    __syncthreads();
    int g = blockIdx.x >> 2, part = blockIdx.x & 3;
    int lo = 0, hi = N_NODES;
    while (lo < hi) { int mid = (lo + hi) >> 1; if (batch[mid] < g) lo = mid + 1; else hi = mid; }
    int lo2 = lo, hi2 = N_NODES;
    while (lo2 < hi2) { int mid = (lo2 + hi2) >> 1; if (batch[mid] < g + 1) lo2 = mid + 1; else hi2 = mid; }
    int len = lo2 - lo;
    if (part == 0 && t == 0) gcnt[g] = (float)len;
    int n0 = lo + (len * part) / 4, n1 = lo + (len * (part + 1)) / 4;
    int c = t & 63, r = t >> 6;
    float sc = ssc[c], sh = ssh[c];
    float acc = 0.f;
    for (int node = n0 + r; node < n1; node += 4) {
        float hv = (float)__builtin_bit_cast(_Float16, hn[(size_t)node * 64 + c]);
        acc += fmaxf(hv * sc + sh, 0.f);
    }
    __shared__ float sb[4][64];
    sb[r][c] = acc;
    __syncthreads();
    if (r == 0)
        atomicAdd(&gpool[g * 64 + c], sb[0][c] + sb[1][c] + sb[2][c] + sb[3][c]);
}

// ---------- classifier ----------
__global__ void classify(const float* __restrict__ gpool, const float* __restrict__ gcnt,
                         const float* __restrict__ Wc, const float* __restrict__ bc, float* __restrict__ out) {
    int t = threadIdx.x;
    if (t >= 640) return;
    int b = t / 10, o = t % 10;
    float inv = 1.f / fmaxf(gcnt[b], 1.f);
    float acc = 0.f;
    for (int c = 0; c < 64; ++c) acc += gpool[b * 64 + c] * Wc[c * 10 + o];
    out[t] = acc * inv + bc[o];
}

extern "C" void kernel_launch(void* const* d_in, const int* in_sizes, int n_in,
                              void* d_out, int out_size, void* d_ws, size_t ws_size,
                              hipStream_t stream) {
    (void)in_sizes; (void)n_in; (void)out_size; (void)ws_size;
    const float* x     = (const float*)d_in[0];
    const int*   ei    = (const int*)d_in[1];
    const int*   batch = (const int*)d_in[2];
    const float* W_enc = (const float*)d_in[3];
    const float* b_enc = (const float*)d_in[4];
    const float* Wl    = (const float*)d_in[5];
    const float* bl    = (const float*)d_in[6];
    const float* Wr    = (const float*)d_in[7];
    const float* br    = (const float*)d_in[8];
    const float* att   = (const float*)d_in[9];
    const float* bias  = (const float*)d_in[10];
    const float* gamma = (const float*)d_in[11];
    const float* beta  = (const float*)d_in[12];
    const float* Wc    = (const float*)d_in[13];
    const float* bc    = (const float*)d_in[14];
    float* out = (float*)d_out;

    char* ws = (char*)d_ws;
    size_t off = 0;
    auto A = [&](size_t bytes) { size_t r = off; off += (bytes + 255) & ~(size_t)255; return r; };

    int* row_ptr = (int*)(ws + A((N_NODES + 1) * 4));
    // colv followed immediately by the contiguous zero region (one memset)
    size_t colv_off = A((size_t)EP_EDGES * 4 + 426240);
    int* colv = (int*)(ws + colv_off);
    char* zbase = ws + colv_off + (size_t)EP_EDGES * 4;
    int*   cursor = (int*)(zbase + 128);              // 400000 B  (col pad = zbase+0, 128 B)
    int*   gcur   = (int*)(zbase + 400128);           // 1024 B
    float* bns    = (float*)(zbase + 401152);         // 8192 B (2 layers x 8 reps x 128)
    float* gpool  = (float*)(zbase + 409344);         // 16384 B
    float* gcnt   = (float*)(zbase + 425728);         // 256 B
    const size_t ZBYTES = 426240;

    unsigned short* hn    = (unsigned short*)(ws + A((size_t)N_NODES * 64 * 2));   // f16 [N][64]
    unsigned short* h2buf = (unsigned short*)(ws + A((size_t)N_NODES * 64 * 2));   // f16 [N][64]
    unsigned short* xl = (unsigned short*)(ws + A((size_t)N_NODES * 128 * 2));
    unsigned short* xr = (unsigned short*)(ws + A((size_t)N_NODES * 128 * 2));
    unsigned* ebuf = (unsigned*)(ws + A((size_t)NREP * NB * SUBREG * 4));
    int* bsum  = (int*)(ws + A(512));
    _Float16* Wfrag0 = (_Float16*)(ws + A(16384 * 2));
    _Float16* Wfrag1 = (_Float16*)(ws + A(16384 * 2));
    float* bias0 = (float*)(ws + A(256 * 4));
    float* bias1 = (float*)(ws + A(256 * 4));

    const int* srcv = ei;
    const int* dstv = ei + E_EDGES;

    hipMemsetAsync(zbase, 0, ZBYTES, stream);

    // bucket_scatter ∥ fuse_enc+pack0 ∥ pack1
    scatter_fuse<<<SCATTER_BLKS + 2, 256, 0, stream>>>(srcv, dstv, gcur, ebuf,
                                                       W_enc, b_enc, Wl, bl, Wr, br,
                                                       Wfrag0, bias0, Wfrag1, bias1);
    // bucket_deg ∥ MFMA layer 0 (encoder folded; reads x directly)
    deg_mfma0<<<NREP * NB + NBLK, 256, 0, stream>>>(gcur, ebuf, cursor,
                                                    x, Wfrag0, bias0, xl, xr);
    scan_a<<<98, 1024, 0, stream>>>(cursor, row_ptr, bsum);
    scan_c<<<(N_NODES + 255) / 256, 256, 0, stream>>>(cursor, row_ptr, bsum);
    bucket_fine<<<NREP * NB, 256, 0, stream>>>(gcur, ebuf, cursor, colv);

    aggregate<<<4096, 256, 0, stream>>>((const char*)xl, (const uint4*)xr,
                                        row_ptr, colv, att, bias, hn, bns);
    // MFMA layer 1 (BN of layer 0 fused into staging, f16 input)
    mfma1<<<NBLK, 256, 0, stream>>>(hn, Wfrag1, bias1, bns, gamma, beta, xl, xr);
    aggregate<<<4096, 256, 0, stream>>>((const char*)xl, (const uint4*)xr,
                                        row_ptr, colv, att + 128, bias + 64, h2buf, bns + 1024);

    // pool (BN of layer 1 fused, f16 input) + classifier
    pool2<<<256, 256, 0, stream>>>(h2buf, batch, bns + 1024, gamma + 64, beta + 64, gpool, gcnt);
    classify<<<1, 640, 0, stream>>>(gpool, gcnt, Wc, bc, out);
}